// Round 6
// baseline (200.269 us; speedup 1.0000x reference)
//
#include <hip/hip_runtime.h>
#include <math.h>

// Dims: B=2, H=256, W=256, C=64, heads=8, dh=64, hd=512, dim_out=64.
// Inputs fp32, output fp32 (proven r1/r2). Internals bf16 + MFMA.
//
// attn[b,h,i,j] = (Wk_i^T G[b] Wq_j)/(||k_i|| ||q_j||)*rescale[h],
// G[b] = Xd^T Xd (Gram of 2x2-avg-pooled input).
// out = x@W_eff[b] + bproj + dwconv2(gelu(dwconv1(x@W_pos + bc1d)))
// W_eff[b] = Wv @ blockdiag_h(attn_h^T) @ Wproj,  W_pos = Wv @ Wc1d.
//
// 5 launches; independent stages packed by blockIdx. r6: occupancy fixes —
// 1024 Gram blocks (was 256), 2-level partial reduce, k_final LDS 64->35 KB.

typedef unsigned short u16;
typedef unsigned int u32;
typedef __attribute__((ext_vector_type(8))) short short8;
typedef __attribute__((ext_vector_type(4))) float f32x4;

__device__ __forceinline__ float bf2f(u16 h) { return __uint_as_float(((u32)h) << 16); }
__device__ __forceinline__ u16 f2bf(float f) {
    u32 u = __float_as_uint(f);
    return (u16)((u + 0x7fffu + ((u >> 16) & 1u)) >> 16);
}
__device__ __forceinline__ float rbf(float f) { return bf2f(f2bf(f)); }
__device__ __forceinline__ u32 pk2(float lo, float hi) {
    return (u32)f2bf(lo) | ((u32)f2bf(hi) << 16);
}
__device__ __forceinline__ void unpack8(uint4 v, float* f) {
    u32 a[4] = {v.x, v.y, v.z, v.w};
#pragma unroll
    for (int i = 0; i < 4; ++i) {
        f[2 * i]     = __uint_as_float(a[i] << 16);
        f[2 * i + 1] = __uint_as_float(a[i] & 0xffff0000u);
    }
}
__device__ __forceinline__ float gelu_exact(float v) {
    return 0.5f * v * (1.f + erff(v * 0.70710678118654752f));
}

// ---------------------------------------------------------------------------
// K1: blocks 0..322 weight fp32->bf16; 323..338 Wpos = Wv@Wc1d;
//     339..1362 pool + Gram partials (1024 blocks, 32 pooled tokens each).
__global__ __launch_bounds__(256) void k_front(
    const float* __restrict__ x,
    const float* __restrict__ wq_f, const float* __restrict__ wk_f,
    const float* __restrict__ wv_f, const float* __restrict__ rs_f,
    const float* __restrict__ wp_f, const float* __restrict__ bp_f,
    const float* __restrict__ wc_f, const float* __restrict__ bc_f,
    const float* __restrict__ p1_f, const float* __restrict__ p2_f,
    u32* __restrict__ wb32, float* __restrict__ Wpos,
    u16* __restrict__ xb, float* __restrict__ partials) {
    __shared__ float xvs[32 * 68];
    int blk = blockIdx.x;
    int t = threadIdx.x;
    if (blk < 323) {
        u32 pid = (u32)blk * 256u + t;
        if (pid < 82564u) {
            const float* src; u32 p;
            if      (pid < 16384u) { src = wq_f; p = pid; }
            else if (pid < 32768u) { src = wk_f; p = pid - 16384u; }
            else if (pid < 49152u) { src = wv_f; p = pid - 32768u; }
            else if (pid < 49156u) { src = rs_f; p = pid - 49152u; }
            else if (pid < 65540u) { src = wp_f; p = pid - 49156u; }
            else if (pid < 65572u) { src = bp_f; p = pid - 65540u; }
            else if (pid < 81956u) { src = wc_f; p = pid - 65572u; }
            else if (pid < 81988u) { src = bc_f; p = pid - 81956u; }
            else if (pid < 82276u) { src = p1_f; p = pid - 81988u; }
            else                   { src = p2_f; p = pid - 82276u; }
            wb32[pid] = (u32)f2bf(src[2 * p]) | ((u32)f2bf(src[2 * p + 1]) << 16);
        }
    } else if (blk < 339) {
        int wpid = (blk - 323) * 256 + t;     // 0..4095
        int o = wpid & 63, c = wpid >> 6;
        float s = 0.f;
        for (int k = 0; k < 512; ++k)
            s += rbf(wv_f[c * 512 + k]) * rbf(wc_f[k * 64 + o]);
        Wpos[c * 64 + o] = s;
    } else {
        int pb = blk - 339;                   // 0..1023
        int b = pb >> 9, sub = pb & 511;
        int py = sub >> 2, qx = sub & 3;      // pooled row, quarter
        const size_t rowbase = (size_t)(b * 256 + 2 * py) * 16384 + (size_t)qx * 4096;
#pragma unroll
        for (int i2 = 0; i2 < 2; ++i2) {
            int u = t + 256 * i2;             // 0..511
            int j = u >> 4, cq = u & 15;      // pooled token 0..31, float4 idx
            size_t o0 = rowbase + (size_t)(2 * j) * 64 + cq * 4;
            float4 a0 = *(const float4*)(x + o0);
            float4 a1 = *(const float4*)(x + o0 + 64);
            float4 a2 = *(const float4*)(x + o0 + 16384);
            float4 a3 = *(const float4*)(x + o0 + 16384 + 64);
            *(uint2*)(xb + o0)              = make_uint2(pk2(a0.x, a0.y), pk2(a0.z, a0.w));
            *(uint2*)(xb + o0 + 64)         = make_uint2(pk2(a1.x, a1.y), pk2(a1.z, a1.w));
            *(uint2*)(xb + o0 + 16384)      = make_uint2(pk2(a2.x, a2.y), pk2(a2.z, a2.w));
            *(uint2*)(xb + o0 + 16384 + 64) = make_uint2(pk2(a3.x, a3.y), pk2(a3.z, a3.w));
            float4 s;
            s.x = 0.25f * (a0.x + a1.x + a2.x + a3.x);
            s.y = 0.25f * (a0.y + a1.y + a2.y + a3.y);
            s.z = 0.25f * (a0.z + a1.z + a2.z + a3.z);
            s.w = 0.25f * (a0.w + a1.w + a2.w + a3.w);
            *(float4*)(&xvs[j * 68 + cq * 4]) = s;
        }
        __syncthreads();
        int r0 = (t >> 4) << 2, c0 = (t & 15) << 2;
        float acc[4][4] = {{0.f}};
        for (int P = 0; P < 32; ++P) {
            float4 av = *(const float4*)(&xvs[P * 68 + r0]);
            float4 bv = *(const float4*)(&xvs[P * 68 + c0]);
            float ar[4] = {av.x, av.y, av.z, av.w};
            float br[4] = {bv.x, bv.y, bv.z, bv.w};
#pragma unroll
            for (int i = 0; i < 4; ++i)
#pragma unroll
                for (int j = 0; j < 4; ++j)
                    acc[i][j] += ar[i] * br[j];
        }
        float* outp = partials + (size_t)pb * 4096;
#pragma unroll
        for (int i = 0; i < 4; ++i)
            *(float4*)(&outp[(r0 + i) * 64 + c0]) =
                make_float4(acc[i][0], acc[i][1], acc[i][2], acc[i][3]);
    }
}

// ---------------------------------------------------------------------------
// K2: blocks 0..63 level-1 reduce 1024->16 partial rows (+Weff zero);
//     64..575 pmain (MFMA matvec pbuf = xb@Wpos + bc1d).
__global__ __launch_bounds__(256) void k_mid1(
    const float* __restrict__ partials, float* __restrict__ out16, float* __restrict__ Weff,
    const u16* __restrict__ xb, const float* __restrict__ Wpos,
    const u16* __restrict__ bc1d, u16* __restrict__ pbuf) {
    __shared__ u16 sm[256 * 72];
    int blk = blockIdx.x;
    int t = threadIdx.x;
    if (blk < 64) {
        int gid = blk * 256 + t;              // 0..16383
        if (gid < 8192) Weff[gid] = 0.f;
        int p2 = blk >> 2;                    // 0..15
        int e4 = (blk & 3) * 256 + t;         // float4 index 0..1023
        float4 s = make_float4(0.f, 0.f, 0.f, 0.f);
        for (int i = 0; i < 64; ++i) {
            float4 v = *(const float4*)(&partials[(size_t)(p2 * 64 + i) * 4096 + e4 * 4]);
            s.x += v.x; s.y += v.y; s.z += v.z; s.w += v.w;
        }
        *(float4*)(&out16[(size_t)p2 * 4096 + e4 * 4]) = s;
        return;
    }
    int pb = blk - 64;                        // 0..511
    int lane = t & 63, wv = t >> 6;
    int col = lane & 15, quad = lane >> 4;

    short8 bf[2][4];
#pragma unroll
    for (int kh = 0; kh < 2; ++kh)
#pragma unroll
        for (int nt = 0; nt < 4; ++nt) {
            short8 v;
#pragma unroll
            for (int j = 0; j < 8; ++j)
                v[j] = (short)f2bf(Wpos[(kh * 32 + quad * 8 + j) * 64 + nt * 16 + col]);
            bf[kh][nt] = v;
        }
    float bias[4];
#pragma unroll
    for (int nt = 0; nt < 4; ++nt) bias[nt] = bf2f(bc1d[nt * 16 + col]);

    size_t base = (size_t)pb * 256;
#pragma unroll
    for (int g = 0; g < 4; ++g) {
        int P0 = wv * 64 + g * 16;
        const short8* ap = (const short8*)(xb + (base + P0 + col) * 64);
        short8 a0 = ap[quad];
        short8 a1 = ap[4 + quad];
#pragma unroll
        for (int nt = 0; nt < 4; ++nt) {
            f32x4 acc = {0.f, 0.f, 0.f, 0.f};
            acc = __builtin_amdgcn_mfma_f32_16x16x32_bf16(a0, bf[0][nt], acc, 0, 0, 0);
            acc = __builtin_amdgcn_mfma_f32_16x16x32_bf16(a1, bf[1][nt], acc, 0, 0, 0);
#pragma unroll
            for (int r = 0; r < 4; ++r)
                sm[(P0 + quad * 4 + r) * 72 + nt * 16 + col] = f2bf(acc[r] + bias[nt]);
        }
    }
    __syncthreads();
#pragma unroll
    for (int k = 0; k < 8; ++k) {
        int linear = k * 256 + t;
        int px = linear >> 3, oct = linear & 7;
        uint4 v = *(const uint4*)(&sm[px * 72 + oct * 8]);
        *(uint4*)(pbuf + (base + px) * 64 + oct * 8) = v;
    }
}

// ---------------------------------------------------------------------------
// K3: in-block reduce out16 -> Gs, then T=G@Wq (G@Wk for norms) + col norms.
// 32 blocks: (b, sel, jg).
__global__ __launch_bounds__(256) void k_gwqk_norms(
    const float* __restrict__ out16, const u16* __restrict__ wqb, const u16* __restrict__ wkb,
    float* __restrict__ T, float* __restrict__ nq, float* __restrict__ nk) {
    __shared__ __align__(16) float Gs[64 * 68];
    __shared__ __align__(16) float Ps[64 * 68];
    int blk = blockIdx.x, t = threadIdx.x;
    int b = blk >> 4, sel = (blk >> 3) & 1, jg = blk & 7;
    const u16* Wsel = sel ? wkb : wqb;
#pragma unroll
    for (int q = 0; q < 4; ++q) {
        int idx = q * 256 + t;                // float4 index 0..1023
        float4 s = make_float4(0.f, 0.f, 0.f, 0.f);
        for (int i = 0; i < 8; ++i) {
            float4 v = *(const float4*)(&out16[(size_t)(b * 8 + i) * 4096 + idx * 4]);
            s.x += v.x; s.y += v.y; s.z += v.z; s.w += v.w;
        }
        int row = idx >> 4, col = (idx & 15) * 4;
        *(float4*)(&Gs[row * 68 + col]) = s;
    }
    __syncthreads();
    int c = t >> 2, jq = t & 3;
    int jbase = jg * 64 + jq * 16;
    float Tr[16];
#pragma unroll
    for (int jj = 0; jj < 16; ++jj) Tr[jj] = 0.f;
    for (int k = 0; k < 64; ++k) {
        short8 w0 = *(const short8*)(&Wsel[k * 512 + jbase]);
        short8 w1 = *(const short8*)(&Wsel[k * 512 + jbase + 8]);
        float g = Gs[c * 68 + k];
#pragma unroll
        for (int jj = 0; jj < 8; ++jj) {
            Tr[jj]     += g * bf2f((u16)w0[jj]);
            Tr[8 + jj] += g * bf2f((u16)w1[jj]);
        }
    }
    if (sel == 0) {
#pragma unroll
        for (int q = 0; q < 4; ++q)
            *(float4*)(&T[(size_t)(b * 64 + c) * 512 + jbase + 4 * q]) =
                make_float4(Tr[4 * q], Tr[4 * q + 1], Tr[4 * q + 2], Tr[4 * q + 3]);
    }
    {
        short8 wc0 = *(const short8*)(&Wsel[c * 512 + jbase]);
        short8 wc1 = *(const short8*)(&Wsel[c * 512 + jbase + 8]);
#pragma unroll
        for (int jj = 0; jj < 8; ++jj) {
            Ps[c * 68 + jq * 16 + jj]     = bf2f((u16)wc0[jj]) * Tr[jj];
            Ps[c * 68 + jq * 16 + 8 + jj] = bf2f((u16)wc1[jj]) * Tr[8 + jj];
        }
    }
    __syncthreads();
    if (t < 64) {
        float s = 0.f;
        for (int cc = 0; cc < 64; ++cc) s += Ps[cc * 68 + t];
        float n = fmaxf(sqrtf(fmaxf(s, 0.f)), 1e-12f);
        (sel ? nk : nq)[b * 512 + jg * 64 + t] = n;
    }
}

// ---------------------------------------------------------------------------
// K4: blocks 0..15 fused attn->softmax->P->Weff (atomicAdd); 16..1039 conv1.
__global__ __launch_bounds__(256) void k_mid2(
    const u16* __restrict__ wkb, const u16* __restrict__ wpb, const u16* __restrict__ wvb,
    const u16* __restrict__ rsb,
    const float* __restrict__ T, const float* __restrict__ nq, const float* __restrict__ nk,
    float* __restrict__ Weff,
    const u16* __restrict__ pbuf, const u16* __restrict__ wpe1, u16* __restrict__ tbuf) {
    __shared__ __align__(16) char shm[53248];
    int blk = blockIdx.x, t = threadIdx.x;
    if (blk < 16) {
        float* Ts    = (float*)shm;              // 17408 B, later Pls
        float* attns = (float*)(shm + 17408);    // 17408 B
        u16*   Wks   = (u16*)(shm + 34816);      // 9216 B, later Wvs
        u16*   Wpjs  = (u16*)(shm + 44032);      // 9216 B
        float* Pls = Ts;
        u16*   Wvs = Wks;
        int b = blk >> 3, h = blk & 7;
        {
            int c = t >> 2, j0 = (t & 3) * 16;
#pragma unroll
            for (int q = 0; q < 4; ++q)
                *(float4*)(&Ts[c * 68 + j0 + 4 * q]) =
                    *(const float4*)(&T[(size_t)(b * 64 + c) * 512 + h * 64 + j0 + 4 * q]);
            *(short8*)(&Wks[c * 72 + j0])     = *(const short8*)(&wkb[c * 512 + h * 64 + j0]);
            *(short8*)(&Wks[c * 72 + j0 + 8]) = *(const short8*)(&wkb[c * 512 + h * 64 + j0 + 8]);
            *(short8*)(&Wpjs[c * 72 + j0])     = *(const short8*)(&wpb[(h * 64 + c) * 64 + j0]);
            *(short8*)(&Wpjs[c * 72 + j0 + 8]) = *(const short8*)(&wpb[(h * 64 + c) * 64 + j0 + 8]);
        }
        __syncthreads();
        {
            int i = t >> 2, jq = t & 3;
            float L[16];
#pragma unroll
            for (int jj = 0; jj < 16; ++jj) L[jj] = 0.f;
            for (int c = 0; c < 64; ++c) {
                float wk = bf2f(Wks[c * 72 + i]);
#pragma unroll
                for (int q = 0; q < 4; ++q) {
                    float4 tv = *(const float4*)(&Ts[c * 68 + jq * 16 + 4 * q]);
                    L[4 * q + 0] += wk * tv.x;
                    L[4 * q + 1] += wk * tv.y;
                    L[4 * q + 2] += wk * tv.z;
                    L[4 * q + 3] += wk * tv.w;
                }
            }
            float rs = bf2f(rsb[h]);
            float nki = nk[b * 512 + h * 64 + i];
            float nqv[16];
#pragma unroll
            for (int q = 0; q < 4; ++q) {
                float4 nv = *(const float4*)(&nq[b * 512 + h * 64 + jq * 16 + 4 * q]);
                nqv[4 * q] = nv.x; nqv[4 * q + 1] = nv.y;
                nqv[4 * q + 2] = nv.z; nqv[4 * q + 3] = nv.w;
            }
            float m = -1e30f;
#pragma unroll
            for (int jj = 0; jj < 16; ++jj) {
                L[jj] = L[jj] * rs / (nki * nqv[jj]);
                m = fmaxf(m, L[jj]);
            }
            m = fmaxf(m, __shfl_xor(m, 1));
            m = fmaxf(m, __shfl_xor(m, 2));
            float s = 0.f;
#pragma unroll
            for (int jj = 0; jj < 16; ++jj) {
                L[jj] = __expf(L[jj] - m);
                s += L[jj];
            }
            s += __shfl_xor(s, 1);
            s += __shfl_xor(s, 2);
            float inv = 1.f / s;
#pragma unroll
            for (int q = 0; q < 4; ++q)
                *(float4*)(&attns[i * 68 + jq * 16 + 4 * q]) =
                    make_float4(L[4 * q] * inv, L[4 * q + 1] * inv,
                                L[4 * q + 2] * inv, L[4 * q + 3] * inv);
        }
        __syncthreads();
        {
            int c = t >> 2, j0 = (t & 3) * 16;
            *(short8*)(&Wvs[c * 72 + j0])     = *(const short8*)(&wvb[c * 512 + h * 64 + j0]);
            *(short8*)(&Wvs[c * 72 + j0 + 8]) = *(const short8*)(&wvb[c * 512 + h * 64 + j0 + 8]);
            int j = t >> 2, oq = t & 3;
            float Pl[16];
#pragma unroll
            for (int jj = 0; jj < 16; ++jj) Pl[jj] = 0.f;
            for (int i2 = 0; i2 < 64; ++i2) {
                float a = attns[i2 * 68 + j];
                short8 w0 = *(const short8*)(&Wpjs[i2 * 72 + oq * 16]);
                short8 w1 = *(const short8*)(&Wpjs[i2 * 72 + oq * 16 + 8]);
#pragma unroll
                for (int jj = 0; jj < 8; ++jj) {
                    Pl[jj]     += a * bf2f((u16)w0[jj]);
                    Pl[8 + jj] += a * bf2f((u16)w1[jj]);
                }
            }
#pragma unroll
            for (int q = 0; q < 4; ++q)
                *(float4*)(&Pls[j * 68 + oq * 16 + 4 * q]) =
                    make_float4(Pl[4 * q], Pl[4 * q + 1], Pl[4 * q + 2], Pl[4 * q + 3]);
        }
        __syncthreads();
        {
            int c = t >> 2, oq = t & 3;
            float acc[16];
#pragma unroll
            for (int jj = 0; jj < 16; ++jj) acc[jj] = 0.f;
            for (int j2 = 0; j2 < 64; ++j2) {
                float wv = bf2f(Wvs[c * 72 + j2]);
#pragma unroll
                for (int q = 0; q < 4; ++q) {
                    float4 pv = *(const float4*)(&Pls[j2 * 68 + oq * 16 + 4 * q]);
                    acc[4 * q + 0] += wv * pv.x;
                    acc[4 * q + 1] += wv * pv.y;
                    acc[4 * q + 2] += wv * pv.z;
                    acc[4 * q + 3] += wv * pv.w;
                }
            }
            float* W = Weff + b * 4096 + c * 64 + oq * 16;
#pragma unroll
            for (int jj = 0; jj < 16; ++jj) atomicAdd(&W[jj], acc[jj]);
        }
        return;
    }
    // ---- conv1, cb = blk - 16 ----
    u16* sm = (u16*)shm;
    int cb = blk - 16;
    int b  = cb >> 9;
    int ty = (cb >> 3) & 63;
    int tx = cb & 7;
    int gy0 = ty * 4, gx0 = tx * 32;

    for (int i = t; i < 1632; i += 256) {
        int px = i >> 3, ch = i & 7;
        int hy = px / 34, hx = px - hy * 34;
        int gy = gy0 + hy - 1, gx = gx0 + hx - 1;
        uint4 v = make_uint4(0, 0, 0, 0);
        if ((unsigned)gy < 256u && (unsigned)gx < 256u)
            v = *(const uint4*)(pbuf + ((size_t)((b << 16) + (gy << 8) + gx)) * 64 + ch * 8);
        *(uint4*)(&sm[px * 72 + ch * 8]) = v;
    }
    int oct = t & 7;
    float w[8][9];
#pragma unroll
    for (int j = 0; j < 8; ++j)
#pragma unroll
        for (int k = 0; k < 9; ++k) w[j][k] = bf2f(wpe1[(oct * 8 + j) * 9 + k]);
    __syncthreads();

#pragma unroll
    for (int s = 0; s < 4; ++s) {
        int lp = (t >> 3) + s * 32;
        int ly = lp >> 5, lx = lp & 31;
        float acc[8] = {0.f, 0.f, 0.f, 0.f, 0.f, 0.f, 0.f, 0.f};
#pragma unroll
        for (int dy = 0; dy < 3; ++dy)
#pragma unroll
            for (int dx = 0; dx < 3; ++dx) {
                int hp = (ly + dy) * 34 + lx + dx;
                uint4 v = *(const uint4*)(&sm[hp * 72 + oct * 8]);
                float f[8];
                unpack8(v, f);
                int tap = dy * 3 + dx;
#pragma unroll
                for (int j = 0; j < 8; ++j) acc[j] += f[j] * w[j][tap];
            }
        u32 pk[4];
#pragma unroll
        for (int q = 0; q < 4; ++q)
            pk[q] = pk2(gelu_exact(acc[2 * q]), gelu_exact(acc[2 * q + 1]));
        size_t gpix = (size_t)(b << 16) + ((size_t)(gy0 + ly) << 8) + gx0 + lx;
        *(uint4*)(tbuf + gpix * 64 + oct * 8) = make_uint4(pk[0], pk[1], pk[2], pk[3]);
    }
}

// ---------------------------------------------------------------------------
// K5: out = xb @ Weff[b] + bproj + dwconv3x3(tbuf, Wpe2). LDS aliased:
// halo sm (29.4 KB) and fp32 stage (34.8 KB) share one buffer; conv results
// bridge the phases in registers. 34.8 KB LDS -> 4 blocks/CU.
__global__ __launch_bounds__(256) void k_final(const u16* __restrict__ xb,
                                               const u16* __restrict__ tbuf,
                                               const float* __restrict__ Weff,
                                               const u16* __restrict__ wpe2,
                                               const u16* __restrict__ bproj,
                                               float* __restrict__ out) {
    __shared__ __align__(16) char shm[34816];
    u16* sm = (u16*)shm;                 // 204*72 u16 = 29376 B (phases 1-2)
    float* stage = (float*)shm;          // 128*68 f32 = 34816 B (phases 3+)
    int t = threadIdx.x;
    int blk = blockIdx.x;
    int b  = blk >> 9;
    int ty = (blk >> 3) & 63;
    int tx = blk & 7;
    int gy0 = ty * 4, gx0 = tx * 32;

    for (int i = t; i < 1632; i += 256) {
        int px = i >> 3, ch = i & 7;
        int hy = px / 34, hx = px - hy * 34;
        int gy = gy0 + hy - 1, gx = gx0 + hx - 1;
        uint4 v = make_uint4(0, 0, 0, 0);
        if ((unsigned)gy < 256u && (unsigned)gx < 256u)
            v = *(const uint4*)(tbuf + ((size_t)((b << 16) + (gy << 8) + gx)) * 64 + ch * 8);
        *(uint4*)(&sm[px * 72 + ch * 8]) = v;
    }
    int oct = t & 7;
    float cacc[4][8];
    {
        float w[8][9];
#pragma unroll
        for (int j = 0; j < 8; ++j)
#pragma unroll
            for (int k = 0; k < 9; ++k) w[j][k] = bf2f(wpe2[(oct * 8 + j) * 9 + k]);
        __syncthreads();
#pragma unroll
        for (int s = 0; s < 4; ++s) {
            int lp = (t >> 3) + s * 32;
            int ly = lp >> 5, lx = lp & 31;
#pragma unroll
            for (int j = 0; j < 8; ++j) cacc[s][j] = 0.f;
#pragma unroll
            for (int dy = 0; dy < 3; ++dy)
#pragma unroll
                for (int dx = 0; dx < 3; ++dx) {
                    int hp = (ly + dy) * 34 + lx + dx;
                    uint4 v = *(const uint4*)(&sm[hp * 72 + oct * 8]);
                    float f[8];
                    unpack8(v, f);
                    int tap = dy * 3 + dx;
#pragma unroll
                    for (int j = 0; j < 8; ++j) cacc[s][j] += f[j] * w[j][tap];
                }
        }
    }
    __syncthreads();           // halo dead; stage may now overwrite sm space
#pragma unroll
    for (int s = 0; s < 4; ++s) {
        int lp = (t >> 3) + s * 32;
#pragma unroll
        for (int j = 0; j < 8; ++j)
            stage[lp * 68 + oct * 8 + j] = cacc[s][j];
    }

    int lane = t & 63, wv = t >> 6;
    int col = lane & 15, quad = lane >> 4;
    const float* W = Weff + b * 4096;
    short8 bf[2][4];
#pragma unroll
    for (int kh = 0; kh < 2; ++kh)
#pragma unroll
        for (int nt = 0; nt < 4; ++nt) {
            short8 v;
#pragma unroll
            for (int j = 0; j < 8; ++j)
                v[j] = (short)f2bf(W[(kh * 32 + quad * 8 + j) * 64 + nt * 16 + col]);
            bf[kh][nt] = v;
        }
    float bias[4];
#pragma unroll
    for (int nt = 0; nt < 4; ++nt) bias[nt] = bf2f(bproj[nt * 16 + col]);
    __syncthreads();           // stage fully written

#pragma unroll
    for (int g = 0; g < 2; ++g) {
        int grp = wv * 2 + g;
        int ly = grp >> 1;
        int lxb = (grp & 1) * 16;
        size_t rowpix = (size_t)(b << 16) + ((size_t)(gy0 + ly) << 8) + gx0;
        const short8* ap = (const short8*)(xb + (rowpix + lxb + col) * 64);
        short8 a0 = ap[quad];
        short8 a1 = ap[4 + quad];
#pragma unroll
        for (int nt = 0; nt < 4; ++nt) {
            f32x4 acc = {0.f, 0.f, 0.f, 0.f};
            acc = __builtin_amdgcn_mfma_f32_16x16x32_bf16(a0, bf[0][nt], acc, 0, 0, 0);
            acc = __builtin_amdgcn_mfma_f32_16x16x32_bf16(a1, bf[1][nt], acc, 0, 0, 0);
#pragma unroll
            for (int r = 0; r < 4; ++r) {
                int lp = ly * 32 + lxb + quad * 4 + r;
                stage[lp * 68 + nt * 16 + col] += acc[r] + bias[nt];
            }
        }
    }
    __syncthreads();

#pragma unroll
    for (int k = 0; k < 8; ++k) {
        int linear = k * 256 + t;
        int px = linear >> 4, c4 = linear & 15;
        int ly = px >> 5, lx = px & 31;
        float4 v = *(const float4*)(&stage[px * 68 + c4 * 4]);
        size_t gpix = (size_t)(b << 16) + ((size_t)(gy0 + ly) << 8) + gx0 + lx;
        *(float4*)(out + gpix * 64 + c4 * 4) = v;
    }
}

// ---------------------------------------------------------------------------
extern "C" void kernel_launch(void* const* d_in, const int* in_sizes, int n_in,
                              void* d_out, int out_size, void* d_ws, size_t ws_size,
                              hipStream_t stream) {
    const float* x = (const float*)d_in[0];
    float* out = (float*)d_out;

    char* w = (char*)d_ws;
    size_t off = 0;
    auto alloc = [&](size_t bytes) -> void* {
        void* p = w + off;
        off += (bytes + 255) & ~(size_t)255;
        return p;
    };
    u16* xb = (u16*)alloc((size_t)16777216 * 2);
    u16* wb = (u16*)alloc((size_t)165128 * 2);
    u16* wqb = wb;
    u16* wkb = wqb + 32768;
    u16* wvb = wkb + 32768;
    u16* rsb = wvb + 32768;
    u16* wpb = rsb + 8;
    u16* bpb = wpb + 32768;
    u16* wcb = bpb + 64;
    u16* bcb = wcb + 32768;
    u16* p1b = bcb + 64;
    u16* p2b = p1b + 576;
    (void)wcb;

    float* partials = (float*)alloc((size_t)1024 * 4096 * 4);
    float* out16    = (float*)alloc((size_t)16 * 4096 * 4);
    float* T        = (float*)alloc((size_t)2 * 64 * 512 * 4);
    float* nq       = (float*)alloc((size_t)2 * 512 * 4);
    float* nk       = (float*)alloc((size_t)2 * 512 * 4);
    float* Weff     = (float*)alloc((size_t)2 * 4096 * 4);
    float* Wpos     = (float*)alloc((size_t)4096 * 4);
    u16*   pbuf     = (u16*)alloc((size_t)2 * 65536 * 64 * 2);
    u16*   tbuf     = (u16*)alloc((size_t)2 * 65536 * 64 * 2);

    hipLaunchKernelGGL(k_front, dim3(1363), dim3(256), 0, stream,
                       x,
                       (const float*)d_in[1], (const float*)d_in[2], (const float*)d_in[3],
                       (const float*)d_in[4], (const float*)d_in[5], (const float*)d_in[6],
                       (const float*)d_in[7], (const float*)d_in[8], (const float*)d_in[9],
                       (const float*)d_in[10],
                       (u32*)wb, Wpos, xb, partials);
    hipLaunchKernelGGL(k_mid1, dim3(576), dim3(256), 0, stream,
                       partials, out16, Weff, xb, Wpos, bcb, pbuf);
    hipLaunchKernelGGL(k_gwqk_norms, dim3(32), dim3(256), 0, stream,
                       out16, wqb, wkb, T, nq, nk);
    hipLaunchKernelGGL(k_mid2, dim3(1040), dim3(256), 0, stream,
                       wkb, wpb, wvb, rsb, T, nq, nk, Weff, pbuf, p1b, tbuf);
    hipLaunchKernelGGL(k_final, dim3(1024), dim3(256), 0, stream,
                       xb, tbuf, Weff, p2b, bpb, out);
}